// Round 1
// baseline (3411.885 us; speedup 1.0000x reference)
//
#include <hip/hip_runtime.h>
#include <math.h>

// ---------------- problem constants ----------------
#define NB   16
#define NPTS 4096
#define M1   1024
#define K1   32
#define M2   256
#define K2   64

// d_out float offsets
#define O_P1 0
#define O_F1 (16*3*1024)            // 49152
#define O_P2 (O_F1 + 16*128*1024)   // 2146304
#define O_F2 (O_P2 + 16*3*256)      // 2158592

// workspace byte offsets
#define WS_GIDX1 0
#define WS_GIDX2 (WS_GIDX1 + 16*1024*32*4)
#define WS_W1T   (WS_GIDX2 + 16*256*64*4)
#define WS_W2T   (WS_W1T  + 6*64*4)
#define WS_W3T   (WS_W2T  + 64*64*4)
#define WS_W20T  (WS_W3T  + 64*128*4)
#define WS_W21T  (WS_W20T + 131*128*4)
#define WS_W22T  (WS_W21T + 128*128*4)

#define DEVINL __device__ __forceinline__

DEVINL float4 f4fma(float w, float4 v, float4 a) {
    a.x = fmaf(w, v.x, a.x); a.y = fmaf(w, v.y, a.y);
    a.z = fmaf(w, v.z, a.z); a.w = fmaf(w, v.w, a.w);
    return a;
}
DEVINL float4 f4relub(float4 a, float b) {
    float4 r;
    r.x = fmaxf(a.x + b, 0.f); r.y = fmaxf(a.y + b, 0.f);
    r.z = fmaxf(a.z + b, 0.f); r.w = fmaxf(a.w + b, 0.f);
    return r;
}
DEVINL float f4max(float4 a) { return fmaxf(fmaxf(a.x, a.y), fmaxf(a.z, a.w)); }

// ---------------- weight transpose + BN-gamma fold ----------------
// wt[i][o] = w[o][i] * g[o]
__global__ __launch_bounds__(256) void prep_weights(
    const float* __restrict__ w10, const float* __restrict__ g10,
    const float* __restrict__ w11, const float* __restrict__ g11,
    const float* __restrict__ w12, const float* __restrict__ g12,
    const float* __restrict__ w20, const float* __restrict__ g20,
    const float* __restrict__ w21, const float* __restrict__ g21,
    const float* __restrict__ w22, const float* __restrict__ g22,
    float* __restrict__ w1t, float* __restrict__ w2t, float* __restrict__ w3t,
    float* __restrict__ w20t, float* __restrict__ w21t, float* __restrict__ w22t)
{
    int e0 = blockIdx.x * 256 + threadIdx.x;
    if (e0 < 384)  { int o = e0/6,   i = e0%6;   w1t [i*64  + o] = w10[e0]*g10[o]; return; }
    e0 -= 384;
    if (e0 < 4096) { int o = e0/64,  i = e0%64;  w2t [i*64  + o] = w11[e0]*g11[o]; return; }
    e0 -= 4096;
    if (e0 < 8192) { int o = e0/64,  i = e0%64;  w3t [i*128 + o] = w12[e0]*g12[o]; return; }
    e0 -= 8192;
    if (e0 < 16768){ int o = e0/131, i = e0%131; w20t[i*128 + o] = w20[e0]*g20[o]; return; }
    e0 -= 16768;
    if (e0 < 16384){ int o = e0/128, i = e0%128; w21t[i*128 + o] = w21[e0]*g21[o]; return; }
    e0 -= 16384;
    if (e0 < 32768){ int o = e0/128, i = e0%128; w22t[i*256 + o] = w22[e0]*g22[o]; return; }
}

// ---------------- furthest point sampling ----------------
// one block per batch; exact jnp semantics: seed idx 0, argmax ties -> lowest index.
template<int N, int NP>
__global__ __launch_bounds__(256) void fps_kernel(const float* __restrict__ pts, // [B,3,N]
                                                  float* __restrict__ prop)      // [B,3,NP]
{
    constexpr int PT = N / 256;
    __shared__ float sx[N], sy[N], sz[N];
    __shared__ int sel[NP];
    __shared__ float rd[4];
    __shared__ int   ri[4];
    int tid = threadIdx.x;
    int b = blockIdx.x;
    const float* p = pts + (size_t)b * 3 * N;
    for (int n = tid; n < N; n += 256) { sx[n] = p[n]; sy[n] = p[N+n]; sz[n] = p[2*N+n]; }
    __syncthreads();

    float lx[PT], ly[PT], lz[PT], ld[PT];
    int base = tid * PT;
#pragma unroll
    for (int j = 0; j < PT; ++j) {
        lx[j] = sx[base+j]; ly[j] = sy[base+j]; lz[j] = sz[base+j];
        ld[j] = __builtin_inff();
    }
    if (tid == 0) sel[0] = 0;
    int last = 0;
    for (int s = 1; s < NP; ++s) {
        float qx = sx[last], qy = sy[last], qz = sz[last];
        float bd = -1.0f; int bi = 0x7FFFFFFF;
#pragma unroll
        for (int j = 0; j < PT; ++j) {
            float dx = __fsub_rn(lx[j], qx);
            float dy = __fsub_rn(ly[j], qy);
            float dz = __fsub_rn(lz[j], qz);
            float dd = __fadd_rn(__fadd_rn(__fmul_rn(dx,dx), __fmul_rn(dy,dy)), __fmul_rn(dz,dz));
            float v = fminf(ld[j], dd);
            ld[j] = v;
            if (v > bd) { bd = v; bi = base + j; }   // ascending j keeps lowest idx on tie
        }
#pragma unroll
        for (int mk = 1; mk < 64; mk <<= 1) {
            float od = __shfl_xor(bd, mk);
            int   oi = __shfl_xor(bi, mk);
            if (od > bd || (od == bd && oi < bi)) { bd = od; bi = oi; }
        }
        if ((tid & 63) == 0) { rd[tid >> 6] = bd; ri[tid >> 6] = bi; }
        __syncthreads();
        bd = rd[0]; bi = ri[0];
#pragma unroll
        for (int w = 1; w < 4; ++w) {
            float od = rd[w]; int oi = ri[w];
            if (od > bd || (od == bd && oi < bi)) { bd = od; bi = oi; }
        }
        last = bi;
        if (tid == 0) sel[s] = bi;
        __syncthreads();
    }
    for (int m = tid; m < NP; m += 256) {
        int i = sel[m];
        prop[(size_t)b*3*NP + m]        = sx[i];
        prop[(size_t)b*3*NP + NP + m]   = sy[i];
        prop[(size_t)b*3*NP + 2*NP + m] = sz[i];
    }
}

// ---------------- KNN (k smallest of expanded-form distance, ties -> lowest index) ----------------
// one block per query; repeated argmin selection == top_k set semantics.
template<int N, int K, int M>
__global__ __launch_bounds__(256) void knn_kernel(const float* __restrict__ pts, // [B,3,N]
                                                  const float* __restrict__ qry, // [B,3,M]
                                                  int* __restrict__ gidx)        // [B,M,K]
{
    __shared__ float dbuf[N];
    __shared__ float rd[4];
    __shared__ int   ri[4];
    int tid = threadIdx.x;
    int bm = blockIdx.x;
    int b = bm / M, m = bm % M;
    const float* p = pts + (size_t)b * 3 * N;
    float qx = qry[(size_t)b*3*M + m];
    float qy = qry[(size_t)b*3*M + M + m];
    float qz = qry[(size_t)b*3*M + 2*M + m];
    float sqq = __fadd_rn(__fadd_rn(__fmul_rn(qx,qx), __fmul_rn(qy,qy)), __fmul_rn(qz,qz));
    for (int n = tid; n < N; n += 256) {
        float px = p[n], py = p[N+n], pz = p[2*N+n];
        float sqp = __fadd_rn(__fadd_rn(__fmul_rn(px,px), __fmul_rn(py,py)), __fmul_rn(pz,pz));
        float dot = __fadd_rn(__fadd_rn(__fmul_rn(qx,px), __fmul_rn(qy,py)), __fmul_rn(qz,pz));
        dbuf[n] = __fadd_rn(__fsub_rn(sqq, __fmul_rn(2.0f, dot)), sqp);
    }
    __syncthreads();
    int* gout = gidx + ((size_t)b * M + m) * K;
    for (int r = 0; r < K; ++r) {
        float bd = __builtin_inff(); int bi = 0x7FFFFFFF;
        for (int n = tid; n < N; n += 256) {
            float v = dbuf[n];
            if (v < bd || (v == bd && n < bi)) { bd = v; bi = n; }
        }
#pragma unroll
        for (int mk = 1; mk < 64; mk <<= 1) {
            float od = __shfl_xor(bd, mk);
            int   oi = __shfl_xor(bi, mk);
            if (od < bd || (od == bd && oi < bi)) { bd = od; bi = oi; }
        }
        if ((tid & 63) == 0) { rd[tid >> 6] = bd; ri[tid >> 6] = bi; }
        __syncthreads();
        bd = rd[0]; bi = ri[0];
#pragma unroll
        for (int w = 1; w < 4; ++w) {
            float od = rd[w]; int oi = ri[w];
            if (od < bd || (od == bd && oi < bi)) { bd = od; bi = oi; }
        }
        if (tid == 0) { gout[r] = bi; dbuf[bi] = __builtin_inff(); }
        __syncthreads();
    }
}

// ---------------- layer 1: gather + MLP(6->64->64->128) + maxpool(32) ----------------
// 8 positions per block; weights staged in LDS; per-thread: channel c (0..63), k-quarter kq.
__global__ __launch_bounds__(256) void mlp1_kernel(
    const float* __restrict__ pts,   // [B,3,4096]
    const float* __restrict__ q,     // points1 [B,3,1024]
    const int*   __restrict__ gidx,  // [B,1024,32]
    const float* __restrict__ w1t, const float* __restrict__ w2t, const float* __restrict__ w3t,
    const float* __restrict__ b1, const float* __restrict__ b2, const float* __restrict__ b3,
    float* __restrict__ out)         // feats1 [B,128,1024]
{
    __shared__ __align__(16) float sw1[6*64];
    __shared__ __align__(16) float sw2[64*64];
    __shared__ __align__(16) float sw3[64*128];
    __shared__ float sb1[64], sb2[64], sb3[128];
    __shared__ __align__(16) float sx[6*32];
    __shared__ __align__(16) float sh1[64*36];   // stride 36 keeps 16B rows + breaks bank conflicts
    __shared__ __align__(16) float sh2[64*36];
    __shared__ float spm[128*4];
    __shared__ float sout[128*8];
    __shared__ int   sgi[32];
    __shared__ float sq[3];

    int tid = threadIdx.x;
    for (int e = tid; e < 6*64;   e += 256) sw1[e] = w1t[e];
    for (int e = tid; e < 64*64;  e += 256) sw2[e] = w2t[e];
    for (int e = tid; e < 64*128; e += 256) sw3[e] = w3t[e];
    if (tid < 64) { sb1[tid] = b1[tid]; sb2[tid] = b2[tid]; }
    else if (tid < 192) sb3[tid-64] = b3[tid-64];

    int pid0 = blockIdx.x * 8;
    int b = pid0 >> 10, m0 = pid0 & 1023;
    int c = tid & 63, kq = tid >> 6, kb = kq * 8;
    __syncthreads();

    for (int it = 0; it < 8; ++it) {
        int m = m0 + it;
        if (tid < 32) sgi[tid] = gidx[((size_t)b*1024 + m)*32 + tid];
        else if (tid < 35) sq[tid-32] = q[((size_t)b*3 + (tid-32))*1024 + m];
        __syncthreads();
        if (tid < 192) {
            int cc = tid >> 5, k = tid & 31;
            int gi = sgi[k];
            const float* pb = pts + (size_t)b*3*4096;
            float v = (cc < 3) ? (pb[cc*4096 + gi] - sq[cc]) : pb[(cc-3)*4096 + gi];
            sx[cc*32 + k] = v;
        }
        __syncthreads();
        // L1: 6 -> 64
        float4 a0 = make_float4(0,0,0,0), a1 = make_float4(0,0,0,0);
#pragma unroll
        for (int i = 0; i < 6; ++i) {
            float w = sw1[i*64 + c];
            a0 = f4fma(w, *(const float4*)&sx[i*32 + kb],     a0);
            a1 = f4fma(w, *(const float4*)&sx[i*32 + kb + 4], a1);
        }
        {
            float bias = sb1[c];
            *(float4*)&sh1[c*36 + kb]     = f4relub(a0, bias);
            *(float4*)&sh1[c*36 + kb + 4] = f4relub(a1, bias);
        }
        __syncthreads();
        // L2: 64 -> 64
        a0 = make_float4(0,0,0,0); a1 = make_float4(0,0,0,0);
#pragma unroll 4
        for (int i = 0; i < 64; ++i) {
            float w = sw2[i*64 + c];
            a0 = f4fma(w, *(const float4*)&sh1[i*36 + kb],     a0);
            a1 = f4fma(w, *(const float4*)&sh1[i*36 + kb + 4], a1);
        }
        {
            float bias = sb2[c];
            *(float4*)&sh2[c*36 + kb]     = f4relub(a0, bias);
            *(float4*)&sh2[c*36 + kb + 4] = f4relub(a1, bias);
        }
        __syncthreads();
        // L3: 64 -> 128 (2 channels/thread) + partial max over this thread's 8 k
        float4 aA0 = make_float4(0,0,0,0), aA1 = make_float4(0,0,0,0);
        float4 aB0 = make_float4(0,0,0,0), aB1 = make_float4(0,0,0,0);
#pragma unroll 4
        for (int i = 0; i < 64; ++i) {
            float wA = sw3[i*128 + c], wB = sw3[i*128 + c + 64];
            float4 v0 = *(const float4*)&sh2[i*36 + kb];
            float4 v1 = *(const float4*)&sh2[i*36 + kb + 4];
            aA0 = f4fma(wA, v0, aA0); aA1 = f4fma(wA, v1, aA1);
            aB0 = f4fma(wB, v0, aB0); aB1 = f4fma(wB, v1, aB1);
        }
        // relu(max+bias) == max(relu(+bias)) (monotone, shared bias)
        float mA = fmaxf(fmaxf(f4max(aA0), f4max(aA1)) + sb3[c],      0.f);
        float mB = fmaxf(fmaxf(f4max(aB0), f4max(aB1)) + sb3[c + 64], 0.f);
        spm[c*4 + kq]        = mA;
        spm[(c + 64)*4 + kq] = mB;
        __syncthreads();
        if (tid < 128) {
            float f = fmaxf(fmaxf(spm[tid*4], spm[tid*4+1]), fmaxf(spm[tid*4+2], spm[tid*4+3]));
            sout[tid*8 + it] = f;
        }
        __syncthreads();
    }
    for (int e = tid; e < 128*8; e += 256) {
        int cc = e >> 3, j = e & 7;
        out[((size_t)b*128 + cc)*1024 + m0 + j] = sout[e];
    }
}

// ---------------- layer 2: gather + MLP(131->128->128->256) + maxpool(64) ----------------
// one position per block; weights from global (L2-resident, transposed for coalescing).
__global__ __launch_bounds__(256) void mlp2_kernel(
    const float* __restrict__ p1,   // [B,3,1024]
    const float* __restrict__ f1,   // [B,128,1024]
    const float* __restrict__ q2,   // [B,3,256]
    const int*   __restrict__ gidx, // [B,256,64]
    const float* __restrict__ w20t, const float* __restrict__ w21t, const float* __restrict__ w22t,
    const float* __restrict__ b20, const float* __restrict__ b21, const float* __restrict__ b22,
    float* __restrict__ out)        // feats2 [B,256,256]
{
    __shared__ __align__(16) float xb[131*68];   // x, later reused as h2
    __shared__ __align__(16) float hb[128*68];   // h1
    __shared__ float spm[256*2];
    __shared__ int   sgi[64];
    __shared__ float sq[3];

    int tid = threadIdx.x;
    int b = blockIdx.x >> 8, m = blockIdx.x & 255;
    if (tid < 64) sgi[tid] = gidx[((size_t)b*256 + m)*64 + tid];
    else if (tid < 67) sq[tid-64] = q2[((size_t)b*3 + (tid-64))*256 + m];
    __syncthreads();
    for (int e = tid; e < 131*64; e += 256) {
        int i = e >> 6, k = e & 63;
        int gi = sgi[k];
        float v = (i < 3) ? (p1[((size_t)b*3 + i)*1024 + gi] - sq[i])
                          : f1[((size_t)b*128 + (i-3))*1024 + gi];
        xb[i*68 + k] = v;
    }
    __syncthreads();

    int c = tid & 127, kq = tid >> 7, kb = kq * 32;
    // L1: 131 -> 128
    float4 acc[8];
#pragma unroll
    for (int j = 0; j < 8; ++j) acc[j] = make_float4(0,0,0,0);
#pragma unroll 2
    for (int i = 0; i < 131; ++i) {
        float w = w20t[i*128 + c];
        const float4* xv = (const float4*)&xb[i*68 + kb];
#pragma unroll
        for (int j = 0; j < 8; ++j) acc[j] = f4fma(w, xv[j], acc[j]);
    }
    {
        float bias = b20[c];
        float4* hv = (float4*)&hb[c*68 + kb];
#pragma unroll
        for (int j = 0; j < 8; ++j) hv[j] = f4relub(acc[j], bias);
    }
    __syncthreads();
    // L2: 128 -> 128  (read hb, write into xb)
#pragma unroll
    for (int j = 0; j < 8; ++j) acc[j] = make_float4(0,0,0,0);
#pragma unroll 2
    for (int i = 0; i < 128; ++i) {
        float w = w21t[i*128 + c];
        const float4* xv = (const float4*)&hb[i*68 + kb];
#pragma unroll
        for (int j = 0; j < 8; ++j) acc[j] = f4fma(w, xv[j], acc[j]);
    }
    __syncthreads();   // everyone done reading hb? (we only overwrite xb; but make xb reads of L1 done)
    {
        float bias = b21[c];
        float4* hv = (float4*)&xb[c*68 + kb];
#pragma unroll
        for (int j = 0; j < 8; ++j) hv[j] = f4relub(acc[j], bias);
    }
    __syncthreads();
    // L3: 128 -> 256 (2 channels/thread), maxpool over this thread's 32 k
    float4 aA[8], aB[8];
#pragma unroll
    for (int j = 0; j < 8; ++j) { aA[j] = make_float4(0,0,0,0); aB[j] = make_float4(0,0,0,0); }
#pragma unroll 2
    for (int i = 0; i < 128; ++i) {
        float wA = w22t[i*256 + c], wB = w22t[i*256 + c + 128];
        const float4* xv = (const float4*)&xb[i*68 + kb];
#pragma unroll
        for (int j = 0; j < 8; ++j) {
            float4 v = xv[j];
            aA[j] = f4fma(wA, v, aA[j]);
            aB[j] = f4fma(wB, v, aB[j]);
        }
    }
    float mxA = -__builtin_inff(), mxB = -__builtin_inff();
#pragma unroll
    for (int j = 0; j < 8; ++j) { mxA = fmaxf(mxA, f4max(aA[j])); mxB = fmaxf(mxB, f4max(aB[j])); }
    float mA = fmaxf(mxA + b22[c],       0.f);
    float mB = fmaxf(mxB + b22[c + 128], 0.f);
    spm[c*2 + kq]         = mA;
    spm[(c + 128)*2 + kq] = mB;
    __syncthreads();
    {
        float f = fmaxf(spm[tid*2], spm[tid*2 + 1]);
        out[((size_t)b*256 + tid)*256 + m] = f;
    }
}

// ---------------- launch ----------------
extern "C" void kernel_launch(void* const* d_in, const int* in_sizes, int n_in,
                              void* d_out, int out_size, void* d_ws, size_t ws_size,
                              hipStream_t stream)
{
    const float* pts = (const float*)d_in[0];
    const float* w10 = (const float*)d_in[1];
    const float* g10 = (const float*)d_in[2];
    const float* b10 = (const float*)d_in[3];
    const float* w11 = (const float*)d_in[4];
    const float* g11 = (const float*)d_in[5];
    const float* b11 = (const float*)d_in[6];
    const float* w12 = (const float*)d_in[7];
    const float* g12 = (const float*)d_in[8];
    const float* b12 = (const float*)d_in[9];
    const float* w20 = (const float*)d_in[10];
    const float* g20 = (const float*)d_in[11];
    const float* b20 = (const float*)d_in[12];
    const float* w21 = (const float*)d_in[13];
    const float* g21 = (const float*)d_in[14];
    const float* b21 = (const float*)d_in[15];
    const float* w22 = (const float*)d_in[16];
    const float* g22 = (const float*)d_in[17];
    const float* b22 = (const float*)d_in[18];

    float* out = (float*)d_out;
    char* ws = (char*)d_ws;
    int* gidx1 = (int*)(ws + WS_GIDX1);
    int* gidx2 = (int*)(ws + WS_GIDX2);
    float* w1t  = (float*)(ws + WS_W1T);
    float* w2t  = (float*)(ws + WS_W2T);
    float* w3t  = (float*)(ws + WS_W3T);
    float* w20t = (float*)(ws + WS_W20T);
    float* w21t = (float*)(ws + WS_W21T);
    float* w22t = (float*)(ws + WS_W22T);

    float* p1 = out + O_P1;   // [16,3,1024]
    float* f1 = out + O_F1;   // [16,128,1024]
    float* p2 = out + O_P2;   // [16,3,256]
    float* f2 = out + O_F2;   // [16,256,256]

    prep_weights<<<307, 256, 0, stream>>>(w10, g10, w11, g11, w12, g12,
                                          w20, g20, w21, g21, w22, g22,
                                          w1t, w2t, w3t, w20t, w21t, w22t);

    fps_kernel<4096, 1024><<<NB, 256, 0, stream>>>(pts, p1);
    knn_kernel<4096, 32, 1024><<<NB * 1024, 256, 0, stream>>>(pts, p1, gidx1);
    mlp1_kernel<<<NB * 1024 / 8, 256, 0, stream>>>(pts, p1, gidx1,
                                                   w1t, w2t, w3t, b10, b11, b12, f1);

    fps_kernel<1024, 256><<<NB, 256, 0, stream>>>(p1, p2);
    knn_kernel<1024, 64, 256><<<NB * 256, 256, 0, stream>>>(p1, p2, gidx2);
    mlp2_kernel<<<NB * 256, 256, 0, stream>>>(p1, f1, p2, gidx2,
                                              w20t, w21t, w22t, b20, b21, b22, f2);
}

// Round 2
// 1999.615 us; speedup vs baseline: 1.7063x; 1.7063x over previous
//
#include <hip/hip_runtime.h>
#include <math.h>

// ---------------- problem constants ----------------
#define NB   16
#define NPTS 4096
#define M1   1024
#define K1   32
#define M2   256
#define K2   64

// d_out float offsets
#define O_P1 0
#define O_F1 (16*3*1024)            // 49152
#define O_P2 (O_F1 + 16*128*1024)   // 2146304
#define O_F2 (O_P2 + 16*3*256)      // 2158592

// workspace byte offsets
#define WS_GIDX1 0
#define WS_GIDX2 (WS_GIDX1 + 16*1024*32*4)
#define WS_W1T   (WS_GIDX2 + 16*256*64*4)
#define WS_W2T   (WS_W1T  + 6*64*4)
#define WS_W3T   (WS_W2T  + 64*64*4)
#define WS_W20T  (WS_W3T  + 64*128*4)
#define WS_W21T  (WS_W20T + 131*128*4)
#define WS_W22T  (WS_W21T + 128*128*4)

#define DEVINL __device__ __forceinline__
typedef unsigned long long u64;

DEVINL float4 f4fma(float w, float4 v, float4 a) {
    a.x = fmaf(w, v.x, a.x); a.y = fmaf(w, v.y, a.y);
    a.z = fmaf(w, v.z, a.z); a.w = fmaf(w, v.w, a.w);
    return a;
}
DEVINL float4 f4relub(float4 a, float b) {
    float4 r;
    r.x = fmaxf(a.x + b, 0.f); r.y = fmaxf(a.y + b, 0.f);
    r.z = fmaxf(a.z + b, 0.f); r.w = fmaxf(a.w + b, 0.f);
    return r;
}
DEVINL float f4max(float4 a) { return fmaxf(fmaxf(a.x, a.y), fmaxf(a.z, a.w)); }

DEVINL u64 shflx64(u64 v, int m) {
    unsigned lo = __shfl_xor((unsigned)v, m);
    unsigned hi = __shfl_xor((unsigned)(v >> 32), m);
    return ((u64)hi << 32) | lo;
}
// order-preserving float -> uint mapping (monotone increasing)
DEVINL unsigned fkey(float f) {
    unsigned u = __float_as_uint(f);
    return (u & 0x80000000u) ? ~u : (u | 0x80000000u);
}

// ---------------- weight transpose + BN-gamma fold ----------------
__global__ __launch_bounds__(256) void prep_weights(
    const float* __restrict__ w10, const float* __restrict__ g10,
    const float* __restrict__ w11, const float* __restrict__ g11,
    const float* __restrict__ w12, const float* __restrict__ g12,
    const float* __restrict__ w20, const float* __restrict__ g20,
    const float* __restrict__ w21, const float* __restrict__ g21,
    const float* __restrict__ w22, const float* __restrict__ g22,
    float* __restrict__ w1t, float* __restrict__ w2t, float* __restrict__ w3t,
    float* __restrict__ w20t, float* __restrict__ w21t, float* __restrict__ w22t)
{
    int e0 = blockIdx.x * 256 + threadIdx.x;
    if (e0 < 384)  { int o = e0/6,   i = e0%6;   w1t [i*64  + o] = w10[e0]*g10[o]; return; }
    e0 -= 384;
    if (e0 < 4096) { int o = e0/64,  i = e0%64;  w2t [i*64  + o] = w11[e0]*g11[o]; return; }
    e0 -= 4096;
    if (e0 < 8192) { int o = e0/64,  i = e0%64;  w3t [i*128 + o] = w12[e0]*g12[o]; return; }
    e0 -= 8192;
    if (e0 < 16768){ int o = e0/131, i = e0%131; w20t[i*128 + o] = w20[e0]*g20[o]; return; }
    e0 -= 16768;
    if (e0 < 16384){ int o = e0/128, i = e0%128; w21t[i*128 + o] = w21[e0]*g21[o]; return; }
    e0 -= 16384;
    if (e0 < 32768){ int o = e0/128, i = e0%128; w22t[i*256 + o] = w22[e0]*g22[o]; return; }
}

// ---------------- furthest point sampling ----------------
// one block per batch; exact jnp semantics: seed idx 0, argmax ties -> lowest index.
// one barrier per step: packed u64 (dist_bits<<32 | ~idx), wave butterfly, parity-buffered
// cross-wave slot. dist >= 0 so float bits are monotone; max(~idx) == min(idx) on ties.
template<int N, int NP>
__global__ __launch_bounds__(256) void fps_kernel(const float* __restrict__ pts, // [B,3,N]
                                                  float* __restrict__ prop)      // [B,3,NP]
{
    constexpr int PT = N / 256;
    __shared__ float sx[N], sy[N], sz[N];
    __shared__ int sel[NP];
    __shared__ u64 rbuf[2][4];
    int tid = threadIdx.x;
    int b = blockIdx.x;
    const float* p = pts + (size_t)b * 3 * N;
    for (int n = tid; n < N; n += 256) { sx[n] = p[n]; sy[n] = p[N+n]; sz[n] = p[2*N+n]; }
    __syncthreads();

    float lx[PT], ly[PT], lz[PT], ld[PT];
    int base = tid * PT;
#pragma unroll
    for (int j = 0; j < PT; ++j) {
        lx[j] = sx[base+j]; ly[j] = sy[base+j]; lz[j] = sz[base+j];
        ld[j] = __builtin_inff();
    }
    if (tid == 0) sel[0] = 0;
    int last = 0;
    for (int s = 1; s < NP; ++s) {
        float qx = sx[last], qy = sy[last], qz = sz[last];
        float bd = -1.0f; int bi = 0x7FFFFFFF;
#pragma unroll
        for (int j = 0; j < PT; ++j) {
            float dx = __fsub_rn(lx[j], qx);
            float dy = __fsub_rn(ly[j], qy);
            float dz = __fsub_rn(lz[j], qz);
            float dd = __fadd_rn(__fadd_rn(__fmul_rn(dx,dx), __fmul_rn(dy,dy)), __fmul_rn(dz,dz));
            float v = fminf(ld[j], dd);
            ld[j] = v;
            if (v > bd) { bd = v; bi = base + j; }   // ascending j -> lowest idx on tie
        }
        u64 pk = ((u64)__float_as_uint(bd) << 32) | (unsigned)(~bi);
#pragma unroll
        for (int mk = 1; mk < 64; mk <<= 1) {
            u64 o = shflx64(pk, mk);
            if (o > pk) pk = o;
        }
        if ((tid & 63) == 0) rbuf[s & 1][tid >> 6] = pk;
        __syncthreads();
        u64 g = rbuf[s & 1][0];
#pragma unroll
        for (int w = 1; w < 4; ++w) { u64 o = rbuf[s & 1][w]; if (o > g) g = o; }
        last = (int)(~(unsigned)g);
        if (tid == 0) sel[s] = last;
    }
    __syncthreads();
    for (int m = tid; m < NP; m += 256) {
        int i = sel[m];
        prop[(size_t)b*3*NP + m]        = sx[i];
        prop[(size_t)b*3*NP + NP + m]   = sy[i];
        prop[(size_t)b*3*NP + 2*NP + m] = sz[i];
    }
}

// ---------------- KNN via radix select ----------------
// one block per query. k smallest of the expanded-form distance, ties -> lowest index.
// 4 rounds of 8-bit MSB radix on order-preserving keys -> exact K-th smallest key (pivot),
// then compact (key < pivot) + fill remaining slots with lowest-index (key == pivot).
// Output order is arbitrary: downstream max-pool is permutation-invariant (set semantics).
template<int N, int K, int M>
__global__ __launch_bounds__(256) void knn_radix(const float* __restrict__ pts, // [B,3,N]
                                                 const float* __restrict__ qry, // [B,3,M]
                                                 int* __restrict__ gidx)        // [B,M,K]
{
    __shared__ unsigned keys[N];
    __shared__ unsigned hist[256];
    __shared__ unsigned wsum[4];
    __shared__ unsigned sbin, sKr, cntL;
    int tid = threadIdx.x;
    int wid = tid >> 6, lane = tid & 63;
    int bm = blockIdx.x;
    int b = bm / M, m = bm % M;
    const float* p = pts + (size_t)b * 3 * N;
    float qx = qry[(size_t)b*3*M + m];
    float qy = qry[(size_t)b*3*M + M + m];
    float qz = qry[(size_t)b*3*M + 2*M + m];
    float sqq = __fadd_rn(__fadd_rn(__fmul_rn(qx,qx), __fmul_rn(qy,qy)), __fmul_rn(qz,qz));
    for (int n = tid; n < N; n += 256) {
        float px = p[n], py = p[N+n], pz = p[2*N+n];
        float sqp = __fadd_rn(__fadd_rn(__fmul_rn(px,px), __fmul_rn(py,py)), __fmul_rn(pz,pz));
        float dot = __fadd_rn(__fadd_rn(__fmul_rn(qx,px), __fmul_rn(qy,py)), __fmul_rn(qz,pz));
        float d = __fadd_rn(__fsub_rn(sqq, __fmul_rn(2.0f, dot)), sqp);
        keys[n] = fkey(d);
    }
    if (tid == 0) cntL = 0;

    unsigned pref = 0, Kr = K;
    for (int shift = 24; shift >= 0; shift -= 8) {
        hist[tid] = 0;
        __syncthreads();
        for (int n = tid; n < N; n += 256) {
            unsigned k = keys[n];
            bool cand = (shift == 24) || ((k >> (shift + 8)) == (pref >> (shift + 8)));
            if (cand) atomicAdd(&hist[(k >> shift) & 255], 1u);
        }
        __syncthreads();
        unsigned h = hist[tid];
        unsigned s = h;
#pragma unroll
        for (int i = 1; i < 64; i <<= 1) {
            unsigned t = __shfl_up(s, i);
            if (lane >= i) s += t;
        }
        if (lane == 63) wsum[wid] = s;
        __syncthreads();
        unsigned off = 0;
        for (int w = 0; w < wid; ++w) off += wsum[w];
        unsigned cum = s + off;                     // count of keys in bins <= tid (candidates)
        if (Kr > cum - h && Kr <= cum) { sbin = (unsigned)tid; sKr = Kr - (cum - h); }
        __syncthreads();
        pref |= (sbin << shift);
        Kr = sKr;
        __syncthreads();
    }
    unsigned pivot = pref;                          // exact K-th smallest key

    int* gout = gidx + ((size_t)b * M + m) * K;
    for (int n = tid; n < N; n += 256) {
        if (keys[n] < pivot) {
            unsigned pos = atomicAdd(&cntL, 1u);
            gout[pos] = n;
        }
    }
    __syncthreads();
    int C = (int)cntL;
    int R = K - C;                                  // >= 1 by construction
    for (int r = 0; r < R; ++r) {
        unsigned bi = 0xFFFFFFFFu;
        for (int n = tid; n < N; n += 256)
            if (keys[n] == pivot && (unsigned)n < bi) bi = (unsigned)n;
#pragma unroll
        for (int mk = 1; mk < 64; mk <<= 1) {
            unsigned o = __shfl_xor(bi, mk);
            if (o < bi) bi = o;
        }
        if (lane == 0) wsum[wid] = bi;
        __syncthreads();
        bi = wsum[0];
#pragma unroll
        for (int w = 1; w < 4; ++w) { unsigned o = wsum[w]; if (o < bi) bi = o; }
        if (tid == 0) { gout[C + r] = (int)bi; keys[bi] = 0xFFFFFFFFu; }  // finite dists never map to FFFFFFFF
        __syncthreads();
    }
}

// ---------------- layer 1: gather + MLP(6->64->64->128) + maxpool(32) ----------------
__global__ __launch_bounds__(256) void mlp1_kernel(
    const float* __restrict__ pts,   // [B,3,4096]
    const float* __restrict__ q,     // points1 [B,3,1024]
    const int*   __restrict__ gidx,  // [B,1024,32]
    const float* __restrict__ w1t, const float* __restrict__ w2t, const float* __restrict__ w3t,
    const float* __restrict__ b1, const float* __restrict__ b2, const float* __restrict__ b3,
    float* __restrict__ out)         // feats1 [B,128,1024]
{
    __shared__ __align__(16) float sw1[6*64];
    __shared__ __align__(16) float sw2[64*64];
    __shared__ __align__(16) float sw3[64*128];
    __shared__ float sb1[64], sb2[64], sb3[128];
    __shared__ __align__(16) float sx[6*32];
    __shared__ __align__(16) float sh1[64*36];
    __shared__ __align__(16) float sh2[64*36];
    __shared__ float spm[128*4];
    __shared__ float sout[128*8];
    __shared__ int   sgi[32];
    __shared__ float sq[3];

    int tid = threadIdx.x;
    for (int e = tid; e < 6*64;   e += 256) sw1[e] = w1t[e];
    for (int e = tid; e < 64*64;  e += 256) sw2[e] = w2t[e];
    for (int e = tid; e < 64*128; e += 256) sw3[e] = w3t[e];
    if (tid < 64) { sb1[tid] = b1[tid]; sb2[tid] = b2[tid]; }
    else if (tid < 192) sb3[tid-64] = b3[tid-64];

    int pid0 = blockIdx.x * 8;
    int b = pid0 >> 10, m0 = pid0 & 1023;
    int c = tid & 63, kq = tid >> 6, kb = kq * 8;
    __syncthreads();

    for (int it = 0; it < 8; ++it) {
        int m = m0 + it;
        if (tid < 32) sgi[tid] = gidx[((size_t)b*1024 + m)*32 + tid];
        else if (tid < 35) sq[tid-32] = q[((size_t)b*3 + (tid-32))*1024 + m];
        __syncthreads();
        if (tid < 192) {
            int cc = tid >> 5, k = tid & 31;
            int gi = sgi[k];
            const float* pb = pts + (size_t)b*3*4096;
            float v = (cc < 3) ? (pb[cc*4096 + gi] - sq[cc]) : pb[(cc-3)*4096 + gi];
            sx[cc*32 + k] = v;
        }
        __syncthreads();
        // L1: 6 -> 64
        float4 a0 = make_float4(0,0,0,0), a1 = make_float4(0,0,0,0);
#pragma unroll
        for (int i = 0; i < 6; ++i) {
            float w = sw1[i*64 + c];
            a0 = f4fma(w, *(const float4*)&sx[i*32 + kb],     a0);
            a1 = f4fma(w, *(const float4*)&sx[i*32 + kb + 4], a1);
        }
        {
            float bias = sb1[c];
            *(float4*)&sh1[c*36 + kb]     = f4relub(a0, bias);
            *(float4*)&sh1[c*36 + kb + 4] = f4relub(a1, bias);
        }
        __syncthreads();
        // L2: 64 -> 64
        a0 = make_float4(0,0,0,0); a1 = make_float4(0,0,0,0);
#pragma unroll 4
        for (int i = 0; i < 64; ++i) {
            float w = sw2[i*64 + c];
            a0 = f4fma(w, *(const float4*)&sh1[i*36 + kb],     a0);
            a1 = f4fma(w, *(const float4*)&sh1[i*36 + kb + 4], a1);
        }
        {
            float bias = sb2[c];
            *(float4*)&sh2[c*36 + kb]     = f4relub(a0, bias);
            *(float4*)&sh2[c*36 + kb + 4] = f4relub(a1, bias);
        }
        __syncthreads();
        // L3: 64 -> 128 (2 channels/thread) + partial max over this thread's 8 k
        float4 aA0 = make_float4(0,0,0,0), aA1 = make_float4(0,0,0,0);
        float4 aB0 = make_float4(0,0,0,0), aB1 = make_float4(0,0,0,0);
#pragma unroll 4
        for (int i = 0; i < 64; ++i) {
            float wA = sw3[i*128 + c], wB = sw3[i*128 + c + 64];
            float4 v0 = *(const float4*)&sh2[i*36 + kb];
            float4 v1 = *(const float4*)&sh2[i*36 + kb + 4];
            aA0 = f4fma(wA, v0, aA0); aA1 = f4fma(wA, v1, aA1);
            aB0 = f4fma(wB, v0, aB0); aB1 = f4fma(wB, v1, aB1);
        }
        float mA = fmaxf(fmaxf(f4max(aA0), f4max(aA1)) + sb3[c],      0.f);
        float mB = fmaxf(fmaxf(f4max(aB0), f4max(aB1)) + sb3[c + 64], 0.f);
        spm[c*4 + kq]        = mA;
        spm[(c + 64)*4 + kq] = mB;
        __syncthreads();
        if (tid < 128) {
            float f = fmaxf(fmaxf(spm[tid*4], spm[tid*4+1]), fmaxf(spm[tid*4+2], spm[tid*4+3]));
            sout[tid*8 + it] = f;
        }
        __syncthreads();
    }
    for (int e = tid; e < 128*8; e += 256) {
        int cc = e >> 3, j = e & 7;
        out[((size_t)b*128 + cc)*1024 + m0 + j] = sout[e];
    }
}

// ---------------- layer 2: gather + MLP(131->128->128->256) + maxpool(64) ----------------
__global__ __launch_bounds__(256) void mlp2_kernel(
    const float* __restrict__ p1,   // [B,3,1024]
    const float* __restrict__ f1,   // [B,128,1024]
    const float* __restrict__ q2,   // [B,3,256]
    const int*   __restrict__ gidx, // [B,256,64]
    const float* __restrict__ w20t, const float* __restrict__ w21t, const float* __restrict__ w22t,
    const float* __restrict__ b20, const float* __restrict__ b21, const float* __restrict__ b22,
    float* __restrict__ out)        // feats2 [B,256,256]
{
    __shared__ __align__(16) float xb[131*68];   // x, later reused as h2
    __shared__ __align__(16) float hb[128*68];   // h1
    __shared__ float spm[256*2];
    __shared__ int   sgi[64];
    __shared__ float sq[3];

    int tid = threadIdx.x;
    int b = blockIdx.x >> 8, m = blockIdx.x & 255;
    if (tid < 64) sgi[tid] = gidx[((size_t)b*256 + m)*64 + tid];
    else if (tid < 67) sq[tid-64] = q2[((size_t)b*3 + (tid-64))*256 + m];
    __syncthreads();
    for (int e = tid; e < 131*64; e += 256) {
        int i = e >> 6, k = e & 63;
        int gi = sgi[k];
        float v = (i < 3) ? (p1[((size_t)b*3 + i)*1024 + gi] - sq[i])
                          : f1[((size_t)b*128 + (i-3))*1024 + gi];
        xb[i*68 + k] = v;
    }
    __syncthreads();

    int c = tid & 127, kq = tid >> 7, kb = kq * 32;
    // L1: 131 -> 128
    float4 acc[8];
#pragma unroll
    for (int j = 0; j < 8; ++j) acc[j] = make_float4(0,0,0,0);
#pragma unroll 2
    for (int i = 0; i < 131; ++i) {
        float w = w20t[i*128 + c];
        const float4* xv = (const float4*)&xb[i*68 + kb];
#pragma unroll
        for (int j = 0; j < 8; ++j) acc[j] = f4fma(w, xv[j], acc[j]);
    }
    {
        float bias = b20[c];
        float4* hv = (float4*)&hb[c*68 + kb];
#pragma unroll
        for (int j = 0; j < 8; ++j) hv[j] = f4relub(acc[j], bias);
    }
    __syncthreads();
    // L2: 128 -> 128  (read hb, write xb)
#pragma unroll
    for (int j = 0; j < 8; ++j) acc[j] = make_float4(0,0,0,0);
#pragma unroll 2
    for (int i = 0; i < 128; ++i) {
        float w = w21t[i*128 + c];
        const float4* xv = (const float4*)&hb[i*68 + kb];
#pragma unroll
        for (int j = 0; j < 8; ++j) acc[j] = f4fma(w, xv[j], acc[j]);
    }
    __syncthreads();
    {
        float bias = b21[c];
        float4* hv = (float4*)&xb[c*68 + kb];
#pragma unroll
        for (int j = 0; j < 8; ++j) hv[j] = f4relub(acc[j], bias);
    }
    __syncthreads();
    // L3: 128 -> 256 (2 channels/thread), maxpool over this thread's 32 k
    float4 aA[8], aB[8];
#pragma unroll
    for (int j = 0; j < 8; ++j) { aA[j] = make_float4(0,0,0,0); aB[j] = make_float4(0,0,0,0); }
#pragma unroll 2
    for (int i = 0; i < 128; ++i) {
        float wA = w22t[i*256 + c], wB = w22t[i*256 + c + 128];
        const float4* xv = (const float4*)&xb[i*68 + kb];
#pragma unroll
        for (int j = 0; j < 8; ++j) {
            float4 v = xv[j];
            aA[j] = f4fma(wA, v, aA[j]);
            aB[j] = f4fma(wB, v, aB[j]);
        }
    }
    float mxA = -__builtin_inff(), mxB = -__builtin_inff();
#pragma unroll
    for (int j = 0; j < 8; ++j) { mxA = fmaxf(mxA, f4max(aA[j])); mxB = fmaxf(mxB, f4max(aB[j])); }
    float mA = fmaxf(mxA + b22[c],       0.f);
    float mB = fmaxf(mxB + b22[c + 128], 0.f);
    spm[c*2 + kq]         = mA;
    spm[(c + 128)*2 + kq] = mB;
    __syncthreads();
    {
        float f = fmaxf(spm[tid*2], spm[tid*2 + 1]);
        out[((size_t)b*256 + tid)*256 + m] = f;
    }
}

// ---------------- launch ----------------
extern "C" void kernel_launch(void* const* d_in, const int* in_sizes, int n_in,
                              void* d_out, int out_size, void* d_ws, size_t ws_size,
                              hipStream_t stream)
{
    const float* pts = (const float*)d_in[0];
    const float* w10 = (const float*)d_in[1];
    const float* g10 = (const float*)d_in[2];
    const float* b10 = (const float*)d_in[3];
    const float* w11 = (const float*)d_in[4];
    const float* g11 = (const float*)d_in[5];
    const float* b11 = (const float*)d_in[6];
    const float* w12 = (const float*)d_in[7];
    const float* g12 = (const float*)d_in[8];
    const float* b12 = (const float*)d_in[9];
    const float* w20 = (const float*)d_in[10];
    const float* g20 = (const float*)d_in[11];
    const float* b20 = (const float*)d_in[12];
    const float* w21 = (const float*)d_in[13];
    const float* g21 = (const float*)d_in[14];
    const float* b21 = (const float*)d_in[15];
    const float* w22 = (const float*)d_in[16];
    const float* g22 = (const float*)d_in[17];
    const float* b22 = (const float*)d_in[18];

    float* out = (float*)d_out;
    char* ws = (char*)d_ws;
    int* gidx1 = (int*)(ws + WS_GIDX1);
    int* gidx2 = (int*)(ws + WS_GIDX2);
    float* w1t  = (float*)(ws + WS_W1T);
    float* w2t  = (float*)(ws + WS_W2T);
    float* w3t  = (float*)(ws + WS_W3T);
    float* w20t = (float*)(ws + WS_W20T);
    float* w21t = (float*)(ws + WS_W21T);
    float* w22t = (float*)(ws + WS_W22T);

    float* p1 = out + O_P1;   // [16,3,1024]
    float* f1 = out + O_F1;   // [16,128,1024]
    float* p2 = out + O_P2;   // [16,3,256]
    float* f2 = out + O_F2;   // [16,256,256]

    prep_weights<<<307, 256, 0, stream>>>(w10, g10, w11, g11, w12, g12,
                                          w20, g20, w21, g21, w22, g22,
                                          w1t, w2t, w3t, w20t, w21t, w22t);

    fps_kernel<4096, 1024><<<NB, 256, 0, stream>>>(pts, p1);
    knn_radix<4096, 32, 1024><<<NB * 1024, 256, 0, stream>>>(pts, p1, gidx1);
    mlp1_kernel<<<NB * 1024 / 8, 256, 0, stream>>>(pts, p1, gidx1,
                                                   w1t, w2t, w3t, b10, b11, b12, f1);

    fps_kernel<1024, 256><<<NB, 256, 0, stream>>>(p1, p2);
    knn_radix<1024, 64, 256><<<NB * 256, 256, 0, stream>>>(p1, p2, gidx2);
    mlp2_kernel<<<NB * 256, 256, 0, stream>>>(p1, f1, p2, gidx2,
                                              w20t, w21t, w22t, b20, b21, b22, f2);
}